// Round 7
// baseline (653.746 us; speedup 1.0000x reference)
//
#include <hip/hip_runtime.h>

typedef __attribute__((ext_vector_type(4))) float f32x4;
typedef __attribute__((ext_vector_type(8))) short bf16x8;
typedef __attribute__((ext_vector_type(4))) unsigned short u16x4;
typedef unsigned short u16;

// Static device intermediates (BSS; fully rewritten every launch).
__device__ static u16   g_xh[(size_t)50176 * 768];     // bf16(x)            77 MB
__device__ static u16   g_wqkvh[(size_t)2304 * 768];   // bf16(w_qkv)       3.5 MB
__device__ static u16   g_wprojh[(size_t)768 * 768];   // bf16(w_proj)      1.2 MB
__device__ static u16   g_qkv[(size_t)50176 * 2304];   // qkv bf16          231 MB
__device__ static u16   g_g1[(size_t)48 * 784 * 256];  // conv1 out bf16     19 MB
__device__ static u16   g_g2[(size_t)48 * 196 * 256];  // conv2 out bf16    4.8 MB
__device__ static u16   g_fh[(size_t)50176 * 768];     // fused bf16         77 MB

static __device__ __forceinline__ u16 f2bf(float x){
  unsigned u = __float_as_uint(x);
  u += 0x7fffu + ((u >> 16) & 1u);
  return (u16)(u >> 16);
}
static __device__ __forceinline__ float bf2f(u16 h){
  return __uint_as_float(((unsigned)h) << 16);
}

// f32 -> bf16 (RNE), vectorized x4, grid-stride.
__global__ __launch_bounds__(256)
void cvt_bf16(const float* __restrict__ in, u16* __restrict__ out, int n4)
{
  int i = blockIdx.x * blockDim.x + threadIdx.x;
  const int stride = gridDim.x * blockDim.x;
  for (; i < n4; i += stride) {
    const f32x4 v = ((const f32x4*)in)[i];
    u16x4 o;
    #pragma unroll
    for (int j = 0; j < 4; j++) o[j] = f2bf(v[j]);
    ((u16x4*)out)[i] = o;
  }
}

// ---------------------------------------------------------------------------
// 8-phase 256x256 GEMM (m201-style), BK=64, 8 waves, C = A * B^T (+bias).
// LDS: 8 half-tile slots x 16KB (2 K-tiles in flight). Half-tiles per K-tile,
// staged in order [B0,B1,A0,A1], prefetch lead delta=7 halves; per phase:
// {ds_read subtile; stage 1 half; [vmcnt @p3]; bar; lgkm(0); 16 MFMA; bar}.
// vmcnt(6) once per K-tile (3 halves = 6 loads outstanding); vmcnt(0) only
// entering the last K-tile. Wave rows interleaved (wm*16+mi*32) so phase p
// reads only A-half (p>>1); B read entirely in phase 0.
// LDS half layout: [128 rows][64 bf16], chunk swizzle c8 ^= row&7 (read side),
// inverse-swizzled global source for the linear global_load_lds (rule #21).
// ---------------------------------------------------------------------------
template<bool BIAS, typename OUT_T>
__global__ __launch_bounds__(512, 2)
void gemm8p(const u16* __restrict__ A0, const u16* __restrict__ Bw,
            const float* __restrict__ bias, OUT_T* __restrict__ C,
            int N, int K, int GX)
{
  __shared__ __align__(16) char ldsb[8 * 16384];
  const int tid = threadIdx.x;
  const int lane = tid & 63;
  const int w = tid >> 6;          // 0..7
  const int wm = w >> 2;           // 0..1
  const int wn = w & 3;            // 0..3
  const int l15 = lane & 15, l4 = lane >> 4;

  // T1 bijective XCD swizzle (m204).
  const int nwg = gridDim.x;
  const int bid = blockIdx.x;
  const int q8 = nwg >> 3, r8 = nwg & 7;
  const int xcd = bid & 7, lid = bid >> 3;
  const int swz = (xcd < r8 ? xcd * (q8 + 1) : r8 * (q8 + 1) + (xcd - r8) * q8) + lid;
  const int bn = swz % GX;
  const int bm = swz / GX;

  const int T = K >> 6;            // K-tiles of 64

  #define GLDS(srcp, ldsoff) __builtin_amdgcn_global_load_lds( \
      (__attribute__((address_space(1))) const void*)(srcp),   \
      (__attribute__((address_space(3))) void*)(ldsb + (ldsoff)), 16, 0, 0)

  // stage half-tile h (2 loads/thread). kind: 0=B0,1=B1,2=A0,3=A1.
  auto stage_half = [&](int h) {
    if (h >= 4 * T) return;
    const int t = h >> 2, kind = h & 3;
    const int slot = (h & 7) << 14;
    #pragma unroll
    for (int j = 0; j < 2; j++) {
      const int prow = (tid >> 3) + (j << 6);            // 0..127
      const int c8 = (tid & 7) ^ (prow & 7);             // inverse swizzle
      const int col = (t << 6) + (c8 << 3);
      const u16* src;
      if (kind < 2) src = Bw + (size_t)(bn * 256 + (kind << 7) + prow) * K + col;
      else          src = A0 + (size_t)(bm * 256 + ((kind - 2) << 7) + prow) * K + col;
      GLDS(src, slot + (j << 13) + tid * 16);
    }
  };

  // ds_read one 16x32 fragment: half-slot base byte, row base in half, ks.
  auto frag = [&](int base, int rbase, int ks) -> bf16x8 {
    const int row = rbase + l15;
    return *(const bf16x8*)(ldsb + base + row * 128 + ((((ks << 2) + l4) ^ (row & 7)) << 4));
  };

  f32x4 acc[8][4];
  #pragma unroll
  for (int i = 0; i < 8; i++)
    #pragma unroll
    for (int j = 0; j < 4; j++) acc[i][j] = (f32x4)0.f;

  // ---- prologue: issue halves 0..6, then ensure K-tile 0 landed ----
  #pragma unroll
  for (int h = 0; h < 7; h++) stage_half(h);
  asm volatile("s_waitcnt vmcnt(6)" ::: "memory");
  __builtin_amdgcn_sched_barrier(0);
  __builtin_amdgcn_s_barrier();
  __builtin_amdgcn_sched_barrier(0);

  bf16x8 bfr[4][2];

  for (int t = 0; t < T; ++t) {
    const int pb = (t & 1) << 16;        // parity base: 4 slots x 16KB
    #pragma unroll
    for (int p = 0; p < 4; p++) {
      // ---- ds-read subtile for this phase ----
      bf16x8 afr[2][2];
      #pragma unroll
      for (int j = 0; j < 2; j++) {
        const int r = wm * 16 + (2 * p + j) * 32;        // 0..240
        const int abase = pb + ((r >> 7) ? 49152 : 32768);
        const int pr = r & 127;
        #pragma unroll
        for (int ks = 0; ks < 2; ks++) afr[j][ks] = frag(abase, pr, ks);
      }
      if (p == 0) {
        #pragma unroll
        for (int ni = 0; ni < 4; ni++) {
          const int r = wn * 16 + ni * 64;
          const int bbase = pb + ((r >> 7) ? 16384 : 0);
          const int pr = r & 127;
          #pragma unroll
          for (int ks = 0; ks < 2; ks++) bfr[ni][ks] = frag(bbase, pr, ks);
        }
      }
      // ---- stage one half-tile (lead = 7 halves) ----
      stage_half(4 * t + p + 7);
      // ---- K-tile boundary wait (once per K-tile, never 0 except last) ----
      if (p == 3) {
        if (t == T - 2) {
          asm volatile("s_waitcnt vmcnt(0)" ::: "memory");
        } else if (t < T - 2) {
          asm volatile("s_waitcnt vmcnt(6)" ::: "memory");
        }
      }
      __builtin_amdgcn_sched_barrier(0);
      __builtin_amdgcn_s_barrier();
      __builtin_amdgcn_sched_barrier(0);
      asm volatile("s_waitcnt lgkmcnt(0)" ::: "memory");
      __builtin_amdgcn_sched_barrier(0);
      __builtin_amdgcn_s_setprio(1);
      #pragma unroll
      for (int j = 0; j < 2; j++)
        #pragma unroll
        for (int ks = 0; ks < 2; ks++)
          #pragma unroll
          for (int ni = 0; ni < 4; ni++)
            acc[2 * p + j][ni] = __builtin_amdgcn_mfma_f32_16x16x32_bf16(
                afr[j][ks], bfr[ni][ks], acc[2 * p + j][ni], 0, 0, 0);
      __builtin_amdgcn_s_setprio(0);
      __builtin_amdgcn_sched_barrier(0);
      __builtin_amdgcn_s_barrier();
      __builtin_amdgcn_sched_barrier(0);
    }
  }
  #undef GLDS

  // ---- epilogue: rows wm*16+mi*32, cols wn*16+ni*64 ----
  #pragma unroll
  for (int mi = 0; mi < 8; mi++)
    #pragma unroll
    for (int ni = 0; ni < 4; ni++) {
      const int col = bn * 256 + wn * 16 + ni * 64 + l15;
      const float bv = BIAS ? bias[col] : 0.f;
      #pragma unroll
      for (int reg = 0; reg < 4; reg++) {
        const int row = bm * 256 + wm * 16 + mi * 32 + (l4 << 2) + reg;
        const float val = acc[mi][ni][reg] + bv;
        if constexpr (sizeof(OUT_T) == 2) C[(size_t)row * N + col] = (OUT_T)f2bf(val);
        else                              C[(size_t)row * N + col] = val;
      }
    }
}

// Grouped conv3x3 stride-1 + bias + 2x2 maxpool -> bf16 (4x4 register patch:
// each input pixel read once instead of 2.25x).
__global__ __launch_bounds__(256)
void conv_pool1(const u16* __restrict__ qkv, const float* __restrict__ wsrc,
                const float* __restrict__ bias, u16* __restrict__ gout)
{
  __shared__ float wl[64 * 145];
  const int g = threadIdx.x;
  const int ty = threadIdx.y;
  const int tid = ty * 64 + g;
  for (int i = tid; i < 9216; i += 256) {
    const int oc = i / 36, rem = i - oc * 36;
    wl[(oc >> 2) * 145 + (oc & 3) * 36 + rem] = wsrc[i];
  }
  __syncthreads();

  const int bt = blockIdx.x;
  const int b = bt / 3, t = bt - b * 3;
  const int p = blockIdx.y * 4 + ty;
  const int y = p / 28, x = p - y * 28;
  const float* wg = &wl[g * 145];

  // 4x4 input patch (iy = 2y-1+i, ix = 2x-1+k), zero-padded.
  f32x4 f[4][4];
  #pragma unroll
  for (int i = 0; i < 4; i++) {
    const int iy = 2 * y - 1 + i;
    #pragma unroll
    for (int k = 0; k < 4; k++) {
      const int ix = 2 * x - 1 + k;
      f32x4 v = (f32x4)0.f;
      if (iy >= 0 && iy < 56 && ix >= 0 && ix < 56) {
        const u16x4 in4 = *(const u16x4*)&qkv[(size_t)(b * 3136 + iy * 56 + ix) * 2304 + t * 768 + 256 + g * 4];
        v[0] = bf2f(in4[0]); v[1] = bf2f(in4[1]); v[2] = bf2f(in4[2]); v[3] = bf2f(in4[3]);
      }
      f[i][k] = v;
    }
  }

  const f32x4 bias4 = *(const f32x4*)&bias[g * 4];
  f32x4 best;
  #pragma unroll
  for (int j = 0; j < 4; j++) best[j] = -3.4e38f;

  #pragma unroll
  for (int dy = 0; dy < 2; dy++)
    #pragma unroll
    for (int dx = 0; dx < 2; dx++) {
      f32x4 c4 = bias4;
      #pragma unroll
      for (int ky = 0; ky < 3; ky++)
        #pragma unroll
        for (int kx = 0; kx < 3; kx++) {
          const f32x4 in4 = f[dy + ky][dx + kx];
          #pragma unroll
          for (int oc = 0; oc < 4; oc++) {
            const float* wp = &wg[oc * 36 + ky * 3 + kx];
            c4[oc] += in4[0] * wp[0] + in4[1] * wp[9] + in4[2] * wp[18] + in4[3] * wp[27];
          }
        }
      #pragma unroll
      for (int j = 0; j < 4; j++) best[j] = fmaxf(best[j], c4[j]);
    }
  u16x4 o4;
  #pragma unroll
  for (int j = 0; j < 4; j++) o4[j] = f2bf(best[j]);
  *(u16x4*)&gout[((size_t)bt * 784 + p) * 256 + g * 4] = o4;
}

// Generic grouped conv3x3 + bias + 2x2 maxpool -> bf16 (used for scale 2).
__global__ __launch_bounds__(256)
void conv_pool(const u16* __restrict__ qkv, const float* __restrict__ wsrc,
               const float* __restrict__ bias, u16* __restrict__ gout,
               int chan0, int Pout, int st, int pd, int dl)
{
  __shared__ float wl[64 * 145];
  const int g = threadIdx.x;
  const int ty = threadIdx.y;
  const int tid = ty * 64 + g;
  for (int i = tid; i < 9216; i += 256) {
    const int oc = i / 36, rem = i - oc * 36;
    wl[(oc >> 2) * 145 + (oc & 3) * 36 + rem] = wsrc[i];
  }
  __syncthreads();

  const int bt = blockIdx.x;
  const int b = bt / 3, t = bt - b * 3;
  const int total = Pout * Pout;
  const int p = blockIdx.y * 4 + ty;
  if (p >= total) return;
  const int y = p / Pout, x = p - y * Pout;

  const f32x4 bias4 = *(const f32x4*)&bias[g * 4];
  f32x4 best;
  #pragma unroll
  for (int j = 0; j < 4; j++) best[j] = -3.4e38f;
  const float* wg = &wl[g * 145];

  #pragma unroll
  for (int dy = 0; dy < 2; dy++)
    #pragma unroll
    for (int dx = 0; dx < 2; dx++) {
      const int py = 2 * y + dy, px = 2 * x + dx;
      f32x4 c4 = bias4;
      #pragma unroll
      for (int ky = 0; ky < 3; ky++) {
        const int iy = py * st - pd + ky * dl;
        if (iy < 0 || iy >= 56) continue;
        #pragma unroll
        for (int kx = 0; kx < 3; kx++) {
          const int ix = px * st - pd + kx * dl;
          if (ix < 0 || ix >= 56) continue;
          const u16x4 in4 = *(const u16x4*)&qkv[(size_t)(b * 3136 + iy * 56 + ix) * 2304 + t * 768 + chan0 + g * 4];
          const float f0 = bf2f(in4[0]), f1 = bf2f(in4[1]), f2 = bf2f(in4[2]), f3 = bf2f(in4[3]);
          #pragma unroll
          for (int oc = 0; oc < 4; oc++) {
            const float* wp = &wg[oc * 36 + ky * 3 + kx];
            c4[oc] += f0 * wp[0] + f1 * wp[9] + f2 * wp[18] + f3 * wp[27];
          }
        }
      }
      #pragma unroll
      for (int j = 0; j < 4; j++) best[j] = fmaxf(best[j], c4[j]);
    }
  u16x4 o4;
  #pragma unroll
  for (int j = 0; j < 4; j++) o4[j] = f2bf(best[j]);
  *(u16x4*)&gout[((size_t)bt * total + p) * 256 + g * 4] = o4;
}

// MFMA windowed attention: one WAVE per (b, region, head); 4 waves/block.
template<int SRC>
__global__ __launch_bounds__(256)
void attn_mfma(const u16* __restrict__ src, u16* __restrict__ fh,
               int side, int Hs, int head_base, int rep)
{
  __shared__ __align__(16) u16 sV[4][64 * 64];
  __shared__ __align__(16) u16 sP[4][64 * 64];
  const int tid = threadIdx.x;
  const int lane = tid & 63;
  const int w = tid >> 6;
  const int nreg = side * side;
  int unit = blockIdx.x * 4 + w;
  const int h = unit & 3; unit >>= 2;
  const int r = unit % nreg;
  const int b = unit / nreg;
  const int hr = r / side, wr = r - hr * side;
  const int l15 = lane & 15, l4 = lane >> 4;

  char* vb = (char*)sV[w];
  char* pb = (char*)sP[w];

  auto gidx = [&](int t, int pp, int c) -> size_t {
    const int py = pp / 7, px = pp - py * 7;
    const int yy = hr * 7 + py, xx = wr * 7 + px;
    if (SRC == 0) return ((size_t)(b * 3136 + yy * 56 + xx)) * 2304 + (size_t)(t * 768 + h * 64 + c);
    else          return ((size_t)(b * 3 + t)) * ((size_t)Hs * Hs * 256) + (size_t)(yy * Hs + xx) * 256 + h * 64 + c;
  };

  // ---- stage V (t=2), rows clamped; swizzle byte ^= ((q>>3)&3)<<5 ----
  for (int i = lane; i < 1024; i += 64) {
    const int q = i >> 4, dc = i & 15;
    const int qs = q > 48 ? 48 : q;
    const u16x4 v4 = *(const u16x4*)&src[gidx(2, qs, dc * 4)];
    *(u16x4*)(vb + ((q * 128 + dc * 8) ^ (((q >> 3) & 3) << 5))) = v4;
  }

  // ---- QK^T ----
  f32x4 s[4][4];
  #pragma unroll
  for (int i = 0; i < 4; i++)
    #pragma unroll
    for (int j = 0; j < 4; j++) s[i][j] = (f32x4)0.f;

  bf16x8 bk[4][2];
  #pragma unroll
  for (int ni = 0; ni < 4; ni++) {
    const int q = ni * 16 + l15;
    const int qs = q > 48 ? 48 : q;
    #pragma unroll
    for (int ks = 0; ks < 2; ks++)
      bk[ni][ks] = *(const bf16x8*)&src[gidx(1, qs, ks * 32 + l4 * 8)];
  }
  #pragma unroll
  for (int mi = 0; mi < 4; mi++) {
    const int p = mi * 16 + l15;
    const int ps = p > 48 ? 48 : p;
    const bf16x8 a0 = *(const bf16x8*)&src[gidx(0, ps, l4 * 8)];
    const bf16x8 a1 = *(const bf16x8*)&src[gidx(0, ps, 32 + l4 * 8)];
    #pragma unroll
    for (int ni = 0; ni < 4; ni++) {
      s[mi][ni] = __builtin_amdgcn_mfma_f32_16x16x32_bf16(a0, bk[ni][0], s[mi][ni], 0, 0, 0);
      s[mi][ni] = __builtin_amdgcn_mfma_f32_16x16x32_bf16(a1, bk[ni][1], s[mi][ni], 0, 0, 0);
    }
  }

  // ---- mask cols q>=49, in-register softmax (unnormalized P) ----
  #pragma unroll
  for (int ni = 0; ni < 4; ni++) {
    const bool bad = (ni * 16 + l15) > 48;
    #pragma unroll
    for (int mi = 0; mi < 4; mi++)
      #pragma unroll
      for (int reg = 0; reg < 4; reg++)
        s[mi][ni][reg] = bad ? -1e30f : s[mi][ni][reg];
  }

  float inv[4][4];
  #pragma unroll
  for (int mi = 0; mi < 4; mi++)
    #pragma unroll
    for (int reg = 0; reg < 4; reg++) {
      float m = fmaxf(fmaxf(s[mi][0][reg], s[mi][1][reg]), fmaxf(s[mi][2][reg], s[mi][3][reg]));
      m = fmaxf(m, __shfl_xor(m, 1));
      m = fmaxf(m, __shfl_xor(m, 2));
      m = fmaxf(m, __shfl_xor(m, 4));
      m = fmaxf(m, __shfl_xor(m, 8));
      float partial = 0.f;
      #pragma unroll
      for (int ni = 0; ni < 4; ni++) {
        const float e = __expf((s[mi][ni][reg] - m) * 0.125f);
        s[mi][ni][reg] = e;
        partial += e;
      }
      partial += __shfl_xor(partial, 1);
      partial += __shfl_xor(partial, 2);
      partial += __shfl_xor(partial, 4);
      partial += __shfl_xor(partial, 8);
      inv[mi][reg] = 1.f / partial;
    }

  // ---- P -> LDS (bf16, XOR-swizzled rows) ----
  #pragma unroll
  for (int mi = 0; mi < 4; mi++)
    #pragma unroll
    for (int ni = 0; ni < 4; ni++)
      #pragma unroll
      for (int reg = 0; reg < 4; reg++) {
        const int row = mi * 16 + l4 * 4 + reg;
        const int col = ni * 16 + l15;
        *(u16*)(pb + ((row * 128 + col * 2) ^ ((row & 7) << 4))) = f2bf(s[mi][ni][reg]);
      }
  __syncthreads();

  // ---- PV ----
  f32x4 o[4][4];
  #pragma unroll
  for (int i = 0; i < 4; i++)
    #pragma unroll
    for (int j = 0; j < 4; j++) o[i][j] = (f32x4)0.f;

  #pragma unroll
  for (int ks = 0; ks < 2; ks++) {
    bf16x8 bv[4];
    #pragma unroll
    for (int ni = 0; ni < 4; ni++)
      #pragma unroll
      for (int j = 0; j < 8; j++) {
        const int q = ks * 32 + l4 * 8 + j;
        bv[ni][j] = *(const short*)(vb + ((q * 128 + (ni * 16 + l15) * 2) ^ (((q >> 3) & 3) << 5)));
      }
    #pragma unroll
    for (int mi = 0; mi < 4; mi++) {
      const int row = mi * 16 + l15;
      const bf16x8 pa = *(const bf16x8*)(pb + ((row * 128 + (ks * 4 + l4) * 16) ^ ((row & 7) << 4)));
      #pragma unroll
      for (int ni = 0; ni < 4; ni++)
        o[mi][ni] = __builtin_amdgcn_mfma_f32_16x16x32_bf16(pa, bv[ni], o[mi][ni], 0, 0, 0);
    }
  }

  // ---- epilogue: scale by 1/sum, bf16, replicate ----
  const int head = head_base + h;
  #pragma unroll
  for (int mi = 0; mi < 4; mi++)
    #pragma unroll
    for (int reg = 0; reg < 4; reg++) {
      const int p = mi * 16 + l4 * 4 + reg;
      if (p >= 49) continue;
      const float iv = inv[mi][reg];
      u16 hv[4];
      #pragma unroll
      for (int ni = 0; ni < 4; ni++) hv[ni] = f2bf(o[mi][ni][reg] * iv);
      for (int m = 0; m < rep; m++) {
        const size_t ob = ((size_t)b * 3136 + (size_t)(m * nreg + r) * 49 + p) * 768 + head * 64 + l15;
        #pragma unroll
        for (int ni = 0; ni < 4; ni++) fh[ob + ni * 16] = hv[ni];
      }
    }
}

extern "C" void kernel_launch(void* const* d_in, const int* in_sizes, int n_in,
                              void* d_out, int out_size, void* d_ws, size_t ws_size,
                              hipStream_t stream)
{
  const float* x      = (const float*)d_in[0];
  const float* w_qkv  = (const float*)d_in[1];
  const float* w_proj = (const float*)d_in[2];
  const float* b_proj = (const float*)d_in[3];
  const float* c1w    = (const float*)d_in[4];
  const float* c1b    = (const float*)d_in[5];
  const float* c2w    = (const float*)d_in[6];
  const float* c2b    = (const float*)d_in[7];
  float* out = (float*)d_out;

  u16 *xh, *wqkvh, *wprojh, *qkvb, *g1, *g2, *fh;
  hipGetSymbolAddress((void**)&xh,     HIP_SYMBOL(g_xh));
  hipGetSymbolAddress((void**)&wqkvh,  HIP_SYMBOL(g_wqkvh));
  hipGetSymbolAddress((void**)&wprojh, HIP_SYMBOL(g_wprojh));
  hipGetSymbolAddress((void**)&qkvb,   HIP_SYMBOL(g_qkv));
  hipGetSymbolAddress((void**)&g1,     HIP_SYMBOL(g_g1));
  hipGetSymbolAddress((void**)&g2,     HIP_SYMBOL(g_g2));
  hipGetSymbolAddress((void**)&fh,     HIP_SYMBOL(g_fh));

  // 0) one-shot bf16 conversions
  cvt_bf16<<<2048, 256, 0, stream>>>(x,      xh,     50176 * 768 / 4);
  cvt_bf16<<<512,  256, 0, stream>>>(w_qkv,  wqkvh,  2304 * 768 / 4);
  cvt_bf16<<<512,  256, 0, stream>>>(w_proj, wprojh, 768 * 768 / 4);

  // 1) QKV GEMM (bf16): (50176,768)@(2304,768)^T -> qkv bf16
  gemm8p<false, u16><<<(50176 / 256) * (2304 / 256), 512, 0, stream>>>(
      xh, wqkvh, nullptr, qkvb, 2304, 768, 2304 / 256);

  // 2) convs for scales 1 and 2 (bf16 out)
  conv_pool1<<<dim3(48, 196), dim3(64, 4), 0, stream>>>(qkvb, c1w, c1b, g1);
  conv_pool<<<dim3(48, 49),  dim3(64, 4), 0, stream>>>(qkvb, c2w, c2b, g2, 512, 14, 2, 2, 2);

  // 3) MFMA windowed attention per scale -> fused bf16
  attn_mfma<0><<<16 * 64 * 4 / 4, 256, 0, stream>>>(qkvb, fh, 8, 56, 0, 1);
  attn_mfma<1><<<16 * 16 * 4 / 4, 256, 0, stream>>>(g1,   fh, 4, 28, 4, 4);
  attn_mfma<1><<<16 * 4 * 4 / 4,  256, 0, stream>>>(g2,   fh, 2, 14, 8, 16);

  // 4) proj GEMM + bias -> out (f32)
  gemm8p<true, float><<<(50176 / 256) * (768 / 256), 512, 0, stream>>>(
      fh, wprojh, b_proj, out, 768, 768, 768 / 256);
}